// Round 5
// baseline (487.589 us; speedup 1.0000x reference)
//
#include <hip/hip_runtime.h>

// ---------------------------------------------------------------------------
// AttnPool: out[1,768] = mean_rows( softmax(QK^T/16) @ V ) @ Wo^T
// M=16384 tokens, D=768, H=256.
// Key identity: mean_m(att @ V) = (colmean of att) @ V, so we only need
// a_bar[j] = (1/M) sum_m exp(S[m,j]*s)/rowsum[m]  -- a 16384-vector.
// Plan:
//   k_conv     : fp32 -> bf16 for x, Wq|Wk|Wv (concat)
//   k_qkv      : [M,768] x [768,768]^T GEMM -> Qb,Kb (bf16), Vf (f32)
//   k_pass1    : S row-sums of exp (max-free; logits ~ +-2)
//   k_rinv     : rinv[m] = 1/(rowsum[m]*M)
//   k_pass2    : colacc[j] += exp(S)*rinv[row]  (atomic col reduce)
//   k_p        : p[h] = sum_j colacc[j]*V[j,h]
//   k_out      : out[d] = sum_h p[h]*Wo[d,h]
// GEMM core = m97 structure: 128x128 tile, BK=32, 4 waves (2x2), LDS via
// global_load_lds width=16, mfma_f32_16x16x32_bf16.
// ---------------------------------------------------------------------------

typedef unsigned short u16;
typedef __attribute__((ext_vector_type(8))) unsigned short u16x8;
typedef __bf16 bf16x8 __attribute__((ext_vector_type(8)));
typedef float f32x4 __attribute__((ext_vector_type(4)));

#define MTOK 16384
#define DDIM 768
#define HDIM 256
#define SM_SCALE 0.0625f   // 1/sqrt(256)

// ---- workspace layout (bytes) ----
#define OFF_XB    (size_t)0                       // bf16 x      [M][768]  25165824
#define OFF_WCAT  (size_t)25165824                // bf16 Wcat   [768][768] 1179648
#define OFF_QB    (size_t)26345472                // bf16 Q      [M][256]   8388608
#define OFF_KB    (size_t)34734080                // bf16 K      [M][256]   8388608
#define OFF_VF    (size_t)43122688                // f32  V      [M][256]  16777216
#define OFF_RS    (size_t)59899904                // f32 rowsum  [M]          65536
#define OFF_RINV  (size_t)59965440                // f32 rinv    [M]          65536
#define OFF_CA    (size_t)60030976                // f32 colacc  [M]          65536
#define OFF_P     (size_t)60096512                // f32 p       [256]         1024
#define WS_NEED   (size_t)60097536

__device__ __forceinline__ u16 f2bf(float f) {
  union { float f; unsigned u; } v; v.f = f;
  unsigned r = v.u + 0x7fffu + ((v.u >> 16) & 1u);
  return (u16)(r >> 16);
}

// ---------------- fp32 -> bf16 conversion, 8 elems/thread -------------------
__global__ void k_conv(const float* __restrict__ src, u16* __restrict__ dst, int n8) {
  int i = blockIdx.x * blockDim.x + threadIdx.x;
  if (i >= n8) return;
  const float4* s = (const float4*)src;
  float4 a = s[2 * i], b = s[2 * i + 1];
  u16x8 o = { f2bf(a.x), f2bf(a.y), f2bf(a.z), f2bf(a.w),
              f2bf(b.x), f2bf(b.y), f2bf(b.z), f2bf(b.w) };
  *(u16x8*)(dst + (size_t)i * 8) = o;
}

// ------------- stage one [128][32] bf16 tile into LDS (1KB x 8 insts) -------
// g must already point at (rowbase, k0). Wave wid issues insts wid*2, wid*2+1.
__device__ __forceinline__ void stage_tile(const u16* __restrict__ g, int ld,
                                           u16* lds, int wid, int lane) {
  const int r = lane >> 2;            // row within 16-row slab
  const int c = (lane & 3) * 8;       // 8 bf16 = 16B per lane
#pragma unroll
  for (int i = 0; i < 2; ++i) {
    int ii = wid * 2 + i;
    const u16* gp = g + (size_t)(ii * 16 + r) * ld + c;
    __builtin_amdgcn_global_load_lds(
        (const __attribute__((address_space(1))) unsigned int*)gp,
        (__attribute__((address_space(3))) unsigned int*)(lds + ii * 512),
        16, 0, 0);
  }
}

// one K-step of the 128x128 MFMA tile (BK=32). acc[4][4] per wave (64x64 quad)
#define KSTEP(APTR, LDA, BPTR, LDB)                                           \
  {                                                                           \
    stage_tile((APTR), (LDA), As, wid, lane);                                 \
    stage_tile((BPTR), (LDB), Bs, wid, lane);                                 \
    __syncthreads();                                                          \
    bf16x8 af[4], bfr[4];                                                     \
    const int kk = (lane >> 4) * 8;                                           \
    _Pragma("unroll") for (int m = 0; m < 4; ++m)                             \
        af[m] = *(const bf16x8*)(As + (wm * 64 + m * 16 + (lane & 15)) * 32 + kk); \
    _Pragma("unroll") for (int n = 0; n < 4; ++n)                             \
        bfr[n] = *(const bf16x8*)(Bs + (wn * 64 + n * 16 + (lane & 15)) * 32 + kk); \
    _Pragma("unroll") for (int m = 0; m < 4; ++m)                             \
        _Pragma("unroll") for (int n = 0; n < 4; ++n)                         \
            acc[m][n] = __builtin_amdgcn_mfma_f32_16x16x32_bf16(              \
                af[m], bfr[n], acc[m][n], 0, 0, 0);                           \
    __syncthreads();                                                          \
  }

// --------------------- QKV projection GEMM ---------------------------------
// C[M,768] = Xb[M,768] @ Wcat^T ; cols 0..255->Qb, 256..511->Kb, 512..767->Vf
__global__ __launch_bounds__(256, 2) void k_qkv(const u16* __restrict__ Xb,
                                                const u16* __restrict__ Wcat,
                                                u16* __restrict__ Qb,
                                                u16* __restrict__ Kb,
                                                float* __restrict__ Vf) {
  __shared__ u16 As[128 * 32];
  __shared__ u16 Bs[128 * 32];
  const int tid = threadIdx.x, wid = tid >> 6, lane = tid & 63;
  const int wm = wid >> 1, wn = wid & 1;
  const int row0 = blockIdx.x * 128;   // token rows
  const int col0 = blockIdx.y * 128;   // output cols (weight rows)
  f32x4 acc[4][4] = {};
  for (int k0 = 0; k0 < DDIM; k0 += 32) {
    KSTEP(Xb + (size_t)row0 * DDIM + k0, DDIM,
          Wcat + (size_t)col0 * DDIM + k0, DDIM);
  }
#pragma unroll
  for (int m = 0; m < 4; ++m)
#pragma unroll
    for (int n = 0; n < 4; ++n) {
      int col = col0 + wn * 64 + n * 16 + (lane & 15);
#pragma unroll
      for (int j = 0; j < 4; ++j) {
        int row = row0 + wm * 64 + m * 16 + (lane >> 4) * 4 + j;
        float v = acc[m][n][j];
        if (col < 256)      Qb[(size_t)row * HDIM + col]         = f2bf(v);
        else if (col < 512) Kb[(size_t)row * HDIM + (col - 256)] = f2bf(v);
        else                Vf[(size_t)row * HDIM + (col - 512)] = v;
      }
    }
}

// --------------------- pass 1: rowsum of exp(S*s) ---------------------------
// grid (128 row-tiles, 8 col groups); each block: 16 col-tiles of 128
__global__ __launch_bounds__(256, 2) void k_pass1(const u16* __restrict__ Qb,
                                                  const u16* __restrict__ Kb,
                                                  float* __restrict__ rowsum) {
  __shared__ u16 As[128 * 32];
  __shared__ u16 Bs[128 * 32];
  const int tid = threadIdx.x, wid = tid >> 6, lane = tid & 63;
  const int wm = wid >> 1, wn = wid & 1;
  const int rowA = blockIdx.x * 128;
  const int jg = blockIdx.y;
  float es[4][4] = {};   // [m][j] partial exp-sums over this block's cols
  for (int it = 0; it < 16; ++it) {
    const int rowB = (jg * 16 + it) * 128;
    f32x4 acc[4][4] = {};
    for (int k0 = 0; k0 < HDIM; k0 += 32) {
      KSTEP(Qb + (size_t)rowA * HDIM + k0, HDIM,
            Kb + (size_t)rowB * HDIM + k0, HDIM);
    }
#pragma unroll
    for (int m = 0; m < 4; ++m)
#pragma unroll
      for (int n = 0; n < 4; ++n)
#pragma unroll
        for (int j = 0; j < 4; ++j)
          es[m][j] += __expf(acc[m][n][j] * SM_SCALE);
  }
#pragma unroll
  for (int m = 0; m < 4; ++m)
#pragma unroll
    for (int j = 0; j < 4; ++j) {
      float v = es[m][j];
      v += __shfl_xor(v, 1);  v += __shfl_xor(v, 2);
      v += __shfl_xor(v, 4);  v += __shfl_xor(v, 8);
      if ((lane & 15) == 0)
        atomicAdd(&rowsum[rowA + wm * 64 + m * 16 + (lane >> 4) * 4 + j], v);
    }
}

__global__ void k_rinv(const float* __restrict__ rowsum, float* __restrict__ rinv) {
  int i = blockIdx.x * 256 + threadIdx.x;
  if (i < MTOK) rinv[i] = 1.0f / (rowsum[i] * (float)MTOK);
}

// --------------------- pass 2: weighted column sums -------------------------
__global__ __launch_bounds__(256, 2) void k_pass2(const u16* __restrict__ Qb,
                                                  const u16* __restrict__ Kb,
                                                  const float* __restrict__ rinv,
                                                  float* __restrict__ colacc) {
  __shared__ u16 As[128 * 32];
  __shared__ u16 Bs[128 * 32];
  const int tid = threadIdx.x, wid = tid >> 6, lane = tid & 63;
  const int wm = wid >> 1, wn = wid & 1;
  const int rowA = blockIdx.x * 128;
  const int rowB = blockIdx.y * 128;
  f32x4 acc[4][4] = {};
  for (int k0 = 0; k0 < HDIM; k0 += 32) {
    KSTEP(Qb + (size_t)rowA * HDIM + k0, HDIM,
          Kb + (size_t)rowB * HDIM + k0, HDIM);
  }
  float r16[4][4];
#pragma unroll
  for (int m = 0; m < 4; ++m)
#pragma unroll
    for (int j = 0; j < 4; ++j)
      r16[m][j] = rinv[rowA + wm * 64 + m * 16 + (lane >> 4) * 4 + j];
  float cs[4] = {};
#pragma unroll
  for (int m = 0; m < 4; ++m)
#pragma unroll
    for (int n = 0; n < 4; ++n)
#pragma unroll
      for (int j = 0; j < 4; ++j)
        cs[n] += __expf(acc[m][n][j] * SM_SCALE) * r16[m][j];
#pragma unroll
  for (int n = 0; n < 4; ++n) {
    float v = cs[n];
    v += __shfl_xor(v, 16);  v += __shfl_xor(v, 32);
    if ((lane >> 4) == 0)
      atomicAdd(&colacc[rowB + wn * 64 + n * 16 + (lane & 15)], v);
  }
}

// --------------------- tail reductions --------------------------------------
__global__ void k_p(const float* __restrict__ colacc, const float* __restrict__ Vf,
                    float* __restrict__ p) {
  const int h = threadIdx.x;          // 256 threads
  const int r0 = blockIdx.x * 128;    // 128 blocks
  float s = 0.f;
  for (int r = r0; r < r0 + 128; ++r)
    s += colacc[r] * Vf[(size_t)r * HDIM + h];
  atomicAdd(&p[h], s);
}

__global__ void k_out(const float* __restrict__ p, const float* __restrict__ Wo,
                      float* __restrict__ out) {
  const int d = blockIdx.x * 256 + threadIdx.x;   // 3 blocks
  if (d >= DDIM) return;
  float s = 0.f;
  for (int h = 0; h < HDIM; ++h) s += p[h] * Wo[(size_t)d * HDIM + h];
  out[d] = s;
}

// ---------------------------------------------------------------------------
extern "C" void kernel_launch(void* const* d_in, const int* in_sizes, int n_in,
                              void* d_out, int out_size, void* d_ws, size_t ws_size,
                              hipStream_t stream) {
  const float* x  = (const float*)d_in[0];   // [M,768]
  const float* Wq = (const float*)d_in[1];   // [256,768]
  const float* Wk = (const float*)d_in[2];
  const float* Wv = (const float*)d_in[3];
  const float* Wo = (const float*)d_in[4];   // [768,256]
  float* out = (float*)d_out;

  char* ws = (char*)d_ws;
  u16*   Xb     = (u16*)(ws + OFF_XB);
  u16*   Wcat   = (u16*)(ws + OFF_WCAT);
  u16*   Qb     = (u16*)(ws + OFF_QB);
  u16*   Kb     = (u16*)(ws + OFF_KB);
  float* Vf     = (float*)(ws + OFF_VF);
  float* rowsum = (float*)(ws + OFF_RS);
  float* rinv   = (float*)(ws + OFF_RINV);
  float* colacc = (float*)(ws + OFF_CA);
  float* p      = (float*)(ws + OFF_P);

  // conversions
  k_conv<<<(MTOK * DDIM / 8 + 255) / 256, 256, 0, stream>>>(x, Xb, MTOK * DDIM / 8);
  const int w8 = HDIM * DDIM / 8;  // 24576 per weight
  k_conv<<<(w8 + 255) / 256, 256, 0, stream>>>(Wq, Wcat + 0 * HDIM * DDIM, w8);
  k_conv<<<(w8 + 255) / 256, 256, 0, stream>>>(Wk, Wcat + 1 * HDIM * DDIM, w8);
  k_conv<<<(w8 + 255) / 256, 256, 0, stream>>>(Wv, Wcat + 2 * HDIM * DDIM, w8);

  // zero accumulators (rowsum, rinv, colacc, p are contiguous)
  hipMemsetAsync(ws + OFF_RS, 0, WS_NEED - OFF_RS, stream);

  // QKV projection
  k_qkv<<<dim3(MTOK / 128, DDIM / 128), 256, 0, stream>>>(Xb, Wcat, Qb, Kb, Vf);

  // softmax row sums, then reciprocal
  k_pass1<<<dim3(MTOK / 128, 8), 256, 0, stream>>>(Qb, Kb, rowsum);
  k_rinv<<<MTOK / 256, 256, 0, stream>>>(rowsum, rinv);

  // weighted column sums
  k_pass2<<<dim3(MTOK / 128, MTOK / 128), 256, 0, stream>>>(Qb, Kb, rinv, colacc);

  // p = a_bar @ V ; out = p @ Wo^T
  k_p<<<MTOK / 128, 256, 0, stream>>>(colacc, Vf, p);
  k_out<<<(DDIM + 255) / 256, 256, 0, stream>>>(p, Wo, out);
}